// Round 1
// baseline (550.440 us; speedup 1.0000x reference)
//
#include <hip/hip_runtime.h>
#include <cstdint>

// Problem constants (fixed by setup_inputs)
#define B_    32
#define CIN   256
#define COUT  512
#define HW    4096
#define NPIX  (B_ * HW)      // 131072
#define NOISE_N (CIN * HW)   // 1048576
#define WN    (COUT * CIN)   // 131072

typedef _Float16 f16;
typedef _Float16 f16x8 __attribute__((ext_vector_type(8)));
typedef float    f32x4 __attribute__((ext_vector_type(4)));

// f^n(SEED) where f(s) = 65539*s + 1 mod 2^32 (exact jump-ahead, matches the
// reference's uint32 cumprod/cumsum closed form).
__device__ __forceinline__ unsigned lcg_seed_after(unsigned n) {
  unsigned A = 1u, Bc = 0u;       // accumulated affine (A,Bc)
  unsigned mA = 65539u, mB = 1u;  // f^(2^i)
  #pragma unroll
  for (int i = 0; i < 21; ++i) {
    if (n & (1u << i)) { A = mA * A; Bc = mA * Bc + mB; }
    mB = mA * mB + mB;
    mA = mA * mA;
  }
  return A * 12345u + Bc;
}

// K0: noise table (C*H*W f32) + fp16 weights
__global__ void k_prep(const float* __restrict__ conv_w,
                       float* __restrict__ noise, f16* __restrict__ w2) {
  const int tid = blockIdx.x * 256 + threadIdx.x;
  if (tid < NOISE_N) {
    const unsigned seed = lcg_seed_after((unsigned)tid + 1u);
    noise[tid] = (float)seed * (float)(0.1 / 4294967295.0);
  } else {
    const int i = tid - NOISE_N;
    if (i < WN) w2[i] = (f16)conv_w[i];
  }
}

// K1: fused  x -> x2=relu(x+noise) fp16:
//   (a) Gram partial G += X2 X2^T over this block's 512-pixel chunk (MFMA)
//   (b) transposed writeback x2t[p][c]
//   (c) per-channel sums
// LDS tile [c=256][p=128] fp16, swizzled: byte = c*256 + ((2p) ^ ((c&7)<<4))
__global__ __launch_bounds__(1024) void k1_gram(
    const float* __restrict__ x, const float* __restrict__ noise,
    f16* __restrict__ x2t, float* __restrict__ gpart,
    float* __restrict__ sums, int npart, int useAtomic) {
  __shared__ unsigned char sm[65536];
  const int t = threadIdx.x;
  const int lane = t & 63;
  const int w = t >> 6;            // 16 waves
  const int wm = w >> 2, wn = w & 3;
  const int bid = blockIdx.x;      // 256 blocks: (b, 512-px chunk)
  const int b = bid >> 3;
  const int hw0 = (bid & 7) << 9;

  const int pslot = t & 31;        // float4 slot -> pixels 4*pslot..+3
  const int crow0 = t >> 5;        // 0..31 base channel

  f32x4 acc[4][4];
  #pragma unroll
  for (int i = 0; i < 4; ++i)
    #pragma unroll
    for (int j = 0; j < 4; ++j)
      acc[i][j] = (f32x4){0.f, 0.f, 0.f, 0.f};
  float csum[8] = {0.f, 0.f, 0.f, 0.f, 0.f, 0.f, 0.f, 0.f};

  for (int s = 0; s < 4; ++s) {
    const int hwS = hw0 + s * 128;
    // ---- stage: relu(x+noise) -> fp16 -> LDS (coalesced 512B rows) ----
    #pragma unroll
    for (int cc = 0; cc < 8; ++cc) {
      const int c = crow0 + 32 * cc;
      const float4 xv = *(const float4*)(x + (((size_t)(b * CIN + c)) << 12) + hwS + 4 * pslot);
      const float4 nv = *(const float4*)(noise + (((size_t)c) << 12) + hwS + 4 * pslot);
      const f16 h0 = (f16)fmaxf(xv.x + nv.x, 0.f);
      const f16 h1 = (f16)fmaxf(xv.y + nv.y, 0.f);
      const f16 h2 = (f16)fmaxf(xv.z + nv.z, 0.f);
      const f16 h3 = (f16)fmaxf(xv.w + nv.w, 0.f);
      csum[cc] += (float)h0 + (float)h1 + (float)h2 + (float)h3;  // stats of the fp16 values
      union { f16 h[2]; unsigned u; } p0, p1;
      p0.h[0] = h0; p0.h[1] = h1; p1.h[0] = h2; p1.h[1] = h3;
      const int byte = c * 256 + ((8 * pslot) ^ ((c & 7) << 4));
      *(uint2*)(sm + byte) = make_uint2(p0.u, p1.u);
    }
    __syncthreads();
    // ---- Gram MFMA: G[c][c'] += sum_p x2[c,p] x2[c',p]  (K = pixels) ----
    #pragma unroll
    for (int ks = 0; ks < 4; ++ks) {
      const int kb = 64 * ks + 16 * (lane >> 4);
      f16x8 af[4];
      #pragma unroll
      for (int mi = 0; mi < 4; ++mi) {
        const int c = 64 * wm + 16 * mi + (lane & 15);
        af[mi] = *(const f16x8*)(sm + c * 256 + (kb ^ ((c & 7) << 4)));
      }
      #pragma unroll
      for (int ni = 0; ni < 4; ++ni) {
        const int c2 = 64 * wn + 16 * ni + (lane & 15);
        const f16x8 bf = *(const f16x8*)(sm + c2 * 256 + (kb ^ ((c2 & 7) << 4)));
        #pragma unroll
        for (int mi = 0; mi < 4; ++mi)
          acc[mi][ni] = __builtin_amdgcn_mfma_f32_16x16x32_f16(af[mi], bf, acc[mi][ni], 0, 0, 0);
      }
    }
    // ---- transpose writeback: x2t[p][c], 64B per thread, fp16 ----
    {
      const int p = t & 127, cg = t >> 7;
      unsigned dw[16];
      #pragma unroll
      for (int j = 0; j < 16; ++j) {
        const int c0 = 32 * cg + 2 * j;
        const unsigned short a  = *(const unsigned short*)(sm + c0 * 256 + ((2 * p) ^ ((c0 & 7) << 4)));
        const unsigned short b2 = *(const unsigned short*)(sm + (c0 + 1) * 256 + ((2 * p) ^ (((c0 + 1) & 7) << 4)));
        dw[j] = (unsigned)a | ((unsigned)b2 << 16);
      }
      char* dst = (char*)x2t + ((size_t)(b * HW + hwS + p)) * 512 + cg * 64;
      ((uint4*)dst)[0] = make_uint4(dw[0],  dw[1],  dw[2],  dw[3]);
      ((uint4*)dst)[1] = make_uint4(dw[4],  dw[5],  dw[6],  dw[7]);
      ((uint4*)dst)[2] = make_uint4(dw[8],  dw[9],  dw[10], dw[11]);
      ((uint4*)dst)[3] = make_uint4(dw[12], dw[13], dw[14], dw[15]);
    }
    __syncthreads();
  }
  // ---- G partial: C/D layout col=lane&15, row=(lane>>4)*4+reg (m91) ----
  {
    float* gp = gpart + (size_t)(bid % npart) * 65536;
    if (useAtomic) {
      #pragma unroll
      for (int mi = 0; mi < 4; ++mi)
        #pragma unroll
        for (int ni = 0; ni < 4; ++ni)
          #pragma unroll
          for (int r = 0; r < 4; ++r) {
            const int m = 64 * wm + 16 * mi + 4 * (lane >> 4) + r;
            const int n = 64 * wn + 16 * ni + (lane & 15);
            atomicAdd(&gp[m * 256 + n], acc[mi][ni][r]);
          }
    } else {
      #pragma unroll
      for (int mi = 0; mi < 4; ++mi)
        #pragma unroll
        for (int ni = 0; ni < 4; ++ni)
          #pragma unroll
          for (int r = 0; r < 4; ++r) {
            const int m = 64 * wm + 16 * mi + 4 * (lane >> 4) + r;
            const int n = 64 * wn + 16 * ni + (lane & 15);
            gp[m * 256 + n] = acc[mi][ni][r];
          }
    }
  }
  // ---- channel sums: LDS reduce (staging buffer is dead now) ----
  {
    float* sl = (float*)sm;  // [256][32]
    #pragma unroll
    for (int cc = 0; cc < 8; ++cc)
      sl[(crow0 + 32 * cc) * 32 + (t & 31)] = csum[cc];
    __syncthreads();
    if (t < 256) {
      float ssum = 0.f;
      #pragma unroll
      for (int i = 0; i < 32; ++i) ssum += sl[t * 32 + i];
      atomicAdd(&sums[t], ssum);
    }
  }
}

// K2a: reduce Gram partials
__global__ void k_greduce(const float* __restrict__ gpart, float* __restrict__ G, int npart) {
  const int i = blockIdx.x * 256 + threadIdx.x;
  float s = 0.f;
  for (int k = 0; k < npart; ++k) s += gpart[(size_t)k * 65536 + i];
  G[i] = s;
}

// K2b: per-o BN fold:  u = w.s/N, var = (w^T G w)/N - u^2,
//      scale = gamma*rsqrt(var+eps), shift = beta - u*scale  (conv_b cancels)
__global__ __launch_bounds__(256) void k_stats(
    const float* __restrict__ G, const float* __restrict__ sums,
    const f16* __restrict__ w2, const float* __restrict__ gamma,
    const float* __restrict__ beta, float* __restrict__ scale,
    float* __restrict__ shift) {
  const int o = blockIdx.x, c = threadIdx.x;
  const float wc = (float)w2[o * 256 + c];
  const float* Gr = G + c * 256;
  const f16* wr = w2 + o * 256;
  float tc = 0.f;
  for (int j = 0; j < 256; ++j) tc += Gr[j] * (float)wr[j];
  float q = wc * tc;
  float uv = wc * sums[c];
  #pragma unroll
  for (int off = 32; off > 0; off >>= 1) {
    q  += __shfl_down(q, off);
    uv += __shfl_down(uv, off);
  }
  __shared__ float rq[4], ru[4];
  const int lane = c & 63, w = c >> 6;
  if (lane == 0) { rq[w] = q; ru[w] = uv; }
  __syncthreads();
  if (c == 0) {
    const float Q = rq[0] + rq[1] + rq[2] + rq[3];
    const float U = ru[0] + ru[1] + ru[2] + ru[3];
    const float invN = 1.f / (float)NPIX;
    const float u = U * invN;
    const float var = Q * invN - u * u;
    const float sc = gamma[o] * rsqrtf(var + 1e-5f);
    scale[o] = sc;
    shift[o] = beta[o] - u * sc;
  }
}

// K3: out[b][o][hw] = (w2 . x2t) * scale[o] + shift[o]
// 128x128 tile, BK=64, 4 waves (64x64 each), global_load_lds width=16 with
// the XOR swizzle pre-applied to the GLOBAL source (LDS dest stays linear).
__global__ __launch_bounds__(256) void k_gemm(
    const f16* __restrict__ w2, const f16* __restrict__ x2t,
    const float* __restrict__ scale, const float* __restrict__ shift,
    float* __restrict__ out) {
  __shared__ unsigned char sm[32768];  // A tile @0, B tile @16384; rows 128B
  const int t = threadIdx.x, lane = t & 63, w = t >> 6;
  const int wm = w >> 1, wn = w & 1;
  const int bid = blockIdx.x;
  const int ot = bid & 3;          // sibling o-tiles adjacent -> share x2t via L2/L3
  const int pt = bid >> 2;
  const int b = pt >> 5;
  const int hw0 = (pt & 31) << 7;
  const int o0 = ot << 7;
  const size_t gp0 = (size_t)b * HW + hw0;

  f32x4 acc[4][4];
  #pragma unroll
  for (int i = 0; i < 4; ++i)
    #pragma unroll
    for (int j = 0; j < 4; ++j)
      acc[i][j] = (f32x4){0.f, 0.f, 0.f, 0.f};

  const int r  = lane >> 3;          // 0..7  (row within 8-row group)
  const int cb = (lane & 7) << 4;    // 0..112 (16B column)
  for (int kt = 0; kt < 4; ++kt) {
    #pragma unroll
    for (int it = 0; it < 4; ++it) {
      const int idx = it * 4 + w;    // 0..15 -> rows idx*8..+7
      const int row = idx * 8 + r;
      const char* sa = (const char*)w2  + (size_t)(o0 + row) * 512 + kt * 128 + (cb ^ (r << 4));
      __builtin_amdgcn_global_load_lds(
          (const __attribute__((address_space(1))) void*)sa,
          (__attribute__((address_space(3))) void*)(sm + idx * 1024), 16, 0, 0);
      const char* sb = (const char*)x2t + (gp0 + row) * 512 + kt * 128 + (cb ^ (r << 4));
      __builtin_amdgcn_global_load_lds(
          (const __attribute__((address_space(1))) void*)sb,
          (__attribute__((address_space(3))) void*)(sm + 16384 + idx * 1024), 16, 0, 0);
    }
    __syncthreads();
    #pragma unroll
    for (int ks = 0; ks < 2; ++ks) {
      const int kb = 64 * ks + 16 * (lane >> 4);
      f16x8 af[4];
      #pragma unroll
      for (int mi = 0; mi < 4; ++mi) {
        const int rowa = 64 * wm + 16 * mi + (lane & 15);
        af[mi] = *(const f16x8*)(sm + rowa * 128 + (kb ^ ((rowa & 7) << 4)));
      }
      #pragma unroll
      for (int ni = 0; ni < 4; ++ni) {
        const int rowb = 64 * wn + 16 * ni + (lane & 15);
        const f16x8 bf = *(const f16x8*)(sm + 16384 + rowb * 128 + (kb ^ ((rowb & 7) << 4)));
        #pragma unroll
        for (int mi = 0; mi < 4; ++mi)
          acc[mi][ni] = __builtin_amdgcn_mfma_f32_16x16x32_f16(af[mi], bf, acc[mi][ni], 0, 0, 0);
      }
    }
    __syncthreads();
  }
  // epilogue: fused BN
  #pragma unroll
  for (int mi = 0; mi < 4; ++mi) {
    #pragma unroll
    for (int rr = 0; rr < 4; ++rr) {
      const int o = o0 + 64 * wm + 16 * mi + 4 * (lane >> 4) + rr;
      const float sc = scale[o], sh = shift[o];
      #pragma unroll
      for (int ni = 0; ni < 4; ++ni) {
        const int hw = hw0 + 64 * wn + 16 * ni + (lane & 15);
        out[(((size_t)(b * COUT + o)) << 12) + hw] = acc[mi][ni][rr] * sc + sh;
      }
    }
  }
}

extern "C" void kernel_launch(void* const* d_in, const int* in_sizes, int n_in,
                              void* d_out, int out_size, void* d_ws, size_t ws_size,
                              hipStream_t stream) {
  (void)in_sizes; (void)n_in; (void)out_size;
  const float* x      = (const float*)d_in[0];
  const float* conv_w = (const float*)d_in[1];
  // d_in[2] = conv_b: cancels in train-mode BN, unused.
  const float* gamma  = (const float*)d_in[3];
  const float* beta   = (const float*)d_in[4];
  float* out = (float*)d_out;
  char* ws = (char*)d_ws;

  // ws layout
  float* noise = (float*)(ws);                              // 4 MiB
  float* G     = (float*)(ws + (4u << 20));                 // 256 KiB
  f16*   w2    = (f16*)  (ws + (4u << 20) + (256u << 10));  // 256 KiB
  float* sums  = (float*)(ws + (4u << 20) + (512u << 10));  // 1 KiB
  float* scale = (float*)(ws + (4u << 20) + (514u << 10));  // 2 KiB
  float* shift = (float*)(ws + (4u << 20) + (517u << 10));  // 2 KiB
  f16*   x2t   = (f16*)  (ws + (5u << 20));                 // 64 MiB
  float* gpart = (float*)(ws + (69u << 20));                // up to 64 MiB

  const size_t avail = ws_size > (69ull << 20) ? ws_size - (69ull << 20) : 0;
  int npart = (int)(avail / (65536ull * sizeof(float)));
  if (npart > 256) npart = 256;
  if (npart < 1) npart = 1;               // (requires ws >= ~70 MiB)
  const int useAtomic = (npart < 256) ? 1 : 0;

  hipMemsetAsync(sums, 0, 256 * sizeof(float), stream);
  if (useAtomic)
    hipMemsetAsync(gpart, 0, (size_t)npart * 65536 * sizeof(float), stream);

  k_prep   <<<4608, 256,  0, stream>>>(conv_w, noise, w2);
  k1_gram  <<<256,  1024, 0, stream>>>(x, noise, x2t, gpart, sums, npart, useAtomic);
  k_greduce<<<256,  256,  0, stream>>>(gpart, G, npart);
  k_stats  <<<COUT, 256,  0, stream>>>(G, sums, w2, gamma, beta, scale, shift);
  k_gemm   <<<4096, 256,  0, stream>>>(w2, x2t, scale, shift, out);
}

// Round 2
// 491.826 us; speedup vs baseline: 1.1192x; 1.1192x over previous
//
#include <hip/hip_runtime.h>
#include <cstdint>

// Problem constants (fixed by setup_inputs)
#define B_    32
#define CIN   256
#define COUT  512
#define HW    4096
#define NPIX  (B_ * HW)      // 131072
#define NOISE_N (CIN * HW)   // 1048576
#define WN    (COUT * CIN)   // 131072

typedef _Float16 f16;
typedef _Float16 f16x8 __attribute__((ext_vector_type(8)));
typedef float    f32x4 __attribute__((ext_vector_type(4)));

// f^n(SEED) where f(s) = 65539*s + 1 mod 2^32 (exact jump-ahead, matches the
// reference's uint32 cumprod/cumsum closed form).
__device__ __forceinline__ unsigned lcg_seed_after(unsigned n) {
  unsigned A = 1u, Bc = 0u;       // accumulated affine (A,Bc)
  unsigned mA = 65539u, mB = 1u;  // f^(2^i)
  #pragma unroll
  for (int i = 0; i < 21; ++i) {
    if (n & (1u << i)) { A = mA * A; Bc = mA * Bc + mB; }
    mB = mA * mB + mB;
    mA = mA * mA;
  }
  return A * 12345u + Bc;
}

// K0: noise table (C*H*W f32) + fp16 weights
__global__ void k_prep(const float* __restrict__ conv_w,
                       float* __restrict__ noise, f16* __restrict__ w2) {
  const int tid = blockIdx.x * 256 + threadIdx.x;
  if (tid < NOISE_N) {
    const unsigned seed = lcg_seed_after((unsigned)tid + 1u);
    noise[tid] = (float)seed * (float)(0.1 / 4294967295.0);
  } else {
    const int i = tid - NOISE_N;
    if (i < WN) w2[i] = (f16)conv_w[i];
  }
}

// Tile byte address: [256 c][32 p] f16, 64 B rows, 16B-chunk XOR swizzle so
// b128 frag reads (rows varying per lane, fixed k-chunk) are conflict-free.
__device__ __forceinline__ int tadr(int c, int chunk) {
  return (c << 6) + (((chunk ^ ((c >> 1) & 3)) & 3) << 4);
}

// K1: fused  x -> x2=relu(x+noise) fp16, 16 pipelined 32-px steps:
//   per step: prefetch x(s+1) -> regs | MFMA Gram(tile[cur]) | transpose-read
//   (tile[cur]) | cvt+ds_write tile[cur^1] | barrier | x2t global store.
//   Loads overlap compute; ONE barrier per step.
__global__ __launch_bounds__(1024) void k1_gram(
    const float* __restrict__ x, const float* __restrict__ noise,
    f16* __restrict__ x2t, float* __restrict__ gpart,
    float* __restrict__ sums, int npart, int useAtomic) {
  __shared__ unsigned char sm[32768];  // two 16 KiB [256][32] f16 tiles
  const int t = threadIdx.x;
  const int lane = t & 63;
  const int w = t >> 6;            // 16 waves
  const int wm = w >> 2, wn = w & 3;
  const int bid = blockIdx.x;      // 256 blocks: (b, 512-px chunk)
  const int b = bid >> 3;
  const int hw0 = (bid & 7) << 9;

  // cvt mapping: thread -> (channel cL, 8 pixels p0..p0+7)
  const int cL = t >> 2;
  const int pq = t & 3;
  const int p0 = pq << 3;
  const float* xrow = x + (((size_t)(b * CIN + cL)) << 12) + hw0 + p0;
  const float* nrow = noise + (((size_t)cL) << 12) + hw0 + p0;
  const int wbyte = tadr(cL, pq);  // b128 write slot (chunk == pq)

  // transpose mapping: thread -> (pixel tp, channels c0..c0+7)
  const int tp = t & 31;
  const int c0 = (t >> 5) << 3;

  f32x4 acc[4][4];
  #pragma unroll
  for (int i = 0; i < 4; ++i)
    #pragma unroll
    for (int j = 0; j < 4; ++j)
      acc[i][j] = (f32x4){0.f, 0.f, 0.f, 0.f};
  float csum = 0.f;

  // prologue: stage step 0
  {
    const float4 xa = *(const float4*)(xrow);
    const float4 xb = *(const float4*)(xrow + 4);
    const float4 na = *(const float4*)(nrow);
    const float4 nb = *(const float4*)(nrow + 4);
    f16x8 hv;
    hv[0] = (f16)fmaxf(xa.x + na.x, 0.f); hv[1] = (f16)fmaxf(xa.y + na.y, 0.f);
    hv[2] = (f16)fmaxf(xa.z + na.z, 0.f); hv[3] = (f16)fmaxf(xa.w + na.w, 0.f);
    hv[4] = (f16)fmaxf(xb.x + nb.x, 0.f); hv[5] = (f16)fmaxf(xb.y + nb.y, 0.f);
    hv[6] = (f16)fmaxf(xb.z + nb.z, 0.f); hv[7] = (f16)fmaxf(xb.w + nb.w, 0.f);
    #pragma unroll
    for (int i = 0; i < 8; ++i) csum += (float)hv[i];
    *(f16x8*)(sm + wbyte) = hv;
  }
  __syncthreads();

  for (int s = 0; s < 16; ++s) {
    const int base = (s & 1) << 14;
    // ---- prefetch next x chunk (consumed in cvt below, pre-barrier) ----
    float4 xa, xb;
    if (s < 15) {
      xa = *(const float4*)(xrow + (s + 1) * 32);
      xb = *(const float4*)(xrow + (s + 1) * 32 + 4);
    }
    // ---- Gram MFMA on tile[cur] (K = 32 px) ----
    {
      const int ch = lane >> 4;
      f16x8 af[4];
      #pragma unroll
      for (int mi = 0; mi < 4; ++mi)
        af[mi] = *(const f16x8*)(sm + base + tadr(wm * 64 + mi * 16 + (lane & 15), ch));
      #pragma unroll
      for (int ni = 0; ni < 4; ++ni) {
        const f16x8 bf = *(const f16x8*)(sm + base + tadr(wn * 64 + ni * 16 + (lane & 15), ch));
        #pragma unroll
        for (int mi = 0; mi < 4; ++mi)
          acc[mi][ni] = __builtin_amdgcn_mfma_f32_16x16x32_f16(af[mi], bf, acc[mi][ni], 0, 0, 0);
      }
    }
    // ---- transpose gather: 8 channels of pixel tp (static indices) ----
    uint4 pk;
    {
      unsigned short vals[8];
      #pragma unroll
      for (int j = 0; j < 8; ++j) {
        const int row = c0 + j;
        const int addr = base + (row << 6) + ((2 * tp) & 15) +
                         ((((tp >> 3) ^ ((row >> 1) & 3)) & 3) << 4);
        vals[j] = *(const unsigned short*)(sm + addr);
      }
      pk.x = (unsigned)vals[0] | ((unsigned)vals[1] << 16);
      pk.y = (unsigned)vals[2] | ((unsigned)vals[3] << 16);
      pk.z = (unsigned)vals[4] | ((unsigned)vals[5] << 16);
      pk.w = (unsigned)vals[6] | ((unsigned)vals[7] << 16);
    }
    // ---- cvt step s+1 into the other buffer ----
    if (s < 15) {
      const float4 na = *(const float4*)(nrow + (s + 1) * 32);
      const float4 nb = *(const float4*)(nrow + (s + 1) * 32 + 4);
      f16x8 hv;
      hv[0] = (f16)fmaxf(xa.x + na.x, 0.f); hv[1] = (f16)fmaxf(xa.y + na.y, 0.f);
      hv[2] = (f16)fmaxf(xa.z + na.z, 0.f); hv[3] = (f16)fmaxf(xa.w + na.w, 0.f);
      hv[4] = (f16)fmaxf(xb.x + nb.x, 0.f); hv[5] = (f16)fmaxf(xb.y + nb.y, 0.f);
      hv[6] = (f16)fmaxf(xb.z + nb.z, 0.f); hv[7] = (f16)fmaxf(xb.w + nb.w, 0.f);
      #pragma unroll
      for (int i = 0; i < 8; ++i) csum += (float)hv[i];
      *(f16x8*)(sm + (base ^ 16384) + wbyte) = hv;
    }
    __syncthreads();
    // ---- x2t store for step s (fire-and-forget, drained by next barrier) ----
    *(uint4*)((char*)x2t + ((size_t)(b * HW + hw0 + s * 32 + tp)) * 512 + (c0 << 1)) = pk;
  }

  // ---- Gram partial writeback: C/D col=lane&15, row=(lane>>4)*4+reg (m91) ----
  {
    float* gp = gpart + (size_t)(bid % npart) * 65536;
    if (useAtomic) {
      #pragma unroll
      for (int mi = 0; mi < 4; ++mi)
        #pragma unroll
        for (int ni = 0; ni < 4; ++ni)
          #pragma unroll
          for (int r = 0; r < 4; ++r) {
            const int m = 64 * wm + 16 * mi + 4 * (lane >> 4) + r;
            const int n = 64 * wn + 16 * ni + (lane & 15);
            atomicAdd(&gp[m * 256 + n], acc[mi][ni][r]);
          }
    } else {
      #pragma unroll
      for (int mi = 0; mi < 4; ++mi)
        #pragma unroll
        for (int ni = 0; ni < 4; ++ni)
          #pragma unroll
          for (int r = 0; r < 4; ++r) {
            const int m = 64 * wm + 16 * mi + 4 * (lane >> 4) + r;
            const int n = 64 * wn + 16 * ni + (lane & 15);
            gp[m * 256 + n] = acc[mi][ni][r];
          }
    }
  }
  // ---- channel sums reduce (tile LDS is dead after final barrier) ----
  {
    float* sl = (float*)sm;  // [256][4]
    sl[(cL << 2) + pq] = csum;
    __syncthreads();
    if (t < 256) {
      const float* r4 = sl + (t << 2);
      atomicAdd(&sums[t], (r4[0] + r4[1]) + (r4[2] + r4[3]));
    }
  }
}

// K2a: reduce Gram partials (unrolled, 4 independent accumulators)
__global__ void k_greduce(const float* __restrict__ gpart, float* __restrict__ G, int npart) {
  const int i = blockIdx.x * 256 + threadIdx.x;
  float s0 = 0.f, s1 = 0.f, s2 = 0.f, s3 = 0.f;
  int k = 0;
  for (; k + 4 <= npart; k += 4) {
    s0 += gpart[(size_t)(k + 0) * 65536 + i];
    s1 += gpart[(size_t)(k + 1) * 65536 + i];
    s2 += gpart[(size_t)(k + 2) * 65536 + i];
    s3 += gpart[(size_t)(k + 3) * 65536 + i];
  }
  for (; k < npart; ++k) s0 += gpart[(size_t)k * 65536 + i];
  G[i] = (s0 + s1) + (s2 + s3);
}

// K2b: per-o BN fold:  u = w.s/N, var = (w^T G w)/N - u^2,
//      scale = gamma*rsqrt(var+eps), shift = beta - u*scale  (conv_b cancels)
__global__ __launch_bounds__(256) void k_stats(
    const float* __restrict__ G, const float* __restrict__ sums,
    const f16* __restrict__ w2, const float* __restrict__ gamma,
    const float* __restrict__ beta, float* __restrict__ scale,
    float* __restrict__ shift) {
  const int o = blockIdx.x, c = threadIdx.x;
  const float wc = (float)w2[o * 256 + c];
  const float4* G4 = (const float4*)(G + (c << 8));
  const f16* wr = w2 + o * 256;
  float tc = 0.f;
  #pragma unroll 4
  for (int j8 = 0; j8 < 32; ++j8) {
    const f16x8 wv = *(const f16x8*)(wr + j8 * 8);
    const float4 ga = G4[2 * j8], gb = G4[2 * j8 + 1];
    tc += ga.x * (float)wv[0] + ga.y * (float)wv[1] + ga.z * (float)wv[2] + ga.w * (float)wv[3]
        + gb.x * (float)wv[4] + gb.y * (float)wv[5] + gb.z * (float)wv[6] + gb.w * (float)wv[7];
  }
  float q = wc * tc;
  float uv = wc * sums[c];
  #pragma unroll
  for (int off = 32; off > 0; off >>= 1) {
    q  += __shfl_down(q, off);
    uv += __shfl_down(uv, off);
  }
  __shared__ float rq[4], ru[4];
  const int lane = c & 63, w = c >> 6;
  if (lane == 0) { rq[w] = q; ru[w] = uv; }
  __syncthreads();
  if (c == 0) {
    const float Q = rq[0] + rq[1] + rq[2] + rq[3];
    const float U = ru[0] + ru[1] + ru[2] + ru[3];
    const float invN = 1.f / (float)NPIX;
    const float u = U * invN;
    const float var = Q * invN - u * u;
    const float sc = gamma[o] * rsqrtf(var + 1e-5f);
    scale[o] = sc;
    shift[o] = beta[o] - u * sc;
  }
}

// K3: out[b][o][hw] = (w2 . x2t) * scale[o] + shift[o]
// 128x128 tile, BK=64, 4 waves; DOUBLE-BUFFERED global_load_lds (T3-min):
// stage(kt+1) issued before compute(kt), one barrier per kt. XOR swizzle
// pre-applied to the GLOBAL source (LDS dest stays linear). T1 XCD swizzle.
__global__ __launch_bounds__(256) void k_gemm(
    const f16* __restrict__ w2, const f16* __restrict__ x2t,
    const float* __restrict__ scale, const float* __restrict__ shift,
    float* __restrict__ out) {
  __shared__ unsigned char sm[65536];  // buf0: A@0 B@16384; buf1: A@32768 B@49152
  const int t = threadIdx.x, lane = t & 63, w = t >> 6;
  const int wm = w >> 1, wn = w & 1;
  // T1: 4096 blocks = 8 XCDs x 512; siblings (same x2t panel) share an XCD L2.
  const int bid = (blockIdx.x & 7) * 512 + (blockIdx.x >> 3);
  const int ot = bid & 3;
  const int pt = bid >> 2;
  const int b = pt >> 5;
  const int hw0 = (pt & 31) << 7;
  const int o0 = ot << 7;
  const size_t gp0 = (size_t)b * HW + hw0;

  f32x4 acc[4][4];
  #pragma unroll
  for (int i = 0; i < 4; ++i)
    #pragma unroll
    for (int j = 0; j < 4; ++j)
      acc[i][j] = (f32x4){0.f, 0.f, 0.f, 0.f};

  const int r  = lane >> 3;          // 0..7  (row within 8-row group)
  const int cb = (lane & 7) << 4;    // 0..112 (16B column)
  const int cbs = cb ^ (r << 4);     // pre-swizzled global column

  #define STAGE(kt, buf)                                                          \
    {                                                                             \
      const int bb = (buf) << 15;                                                 \
      _Pragma("unroll")                                                           \
      for (int it = 0; it < 4; ++it) {                                            \
        const int idx = it * 4 + w;                                               \
        const int row = idx * 8 + r;                                              \
        const char* sa = (const char*)w2 + (size_t)(o0 + row) * 512 + (kt) * 128 + cbs; \
        __builtin_amdgcn_global_load_lds(                                         \
            (const __attribute__((address_space(1))) void*)sa,                    \
            (__attribute__((address_space(3))) void*)(sm + bb + idx * 1024), 16, 0, 0); \
        const char* sb = (const char*)x2t + (gp0 + row) * 512 + (kt) * 128 + cbs; \
        __builtin_amdgcn_global_load_lds(                                         \
            (const __attribute__((address_space(1))) void*)sb,                    \
            (__attribute__((address_space(3))) void*)(sm + bb + 16384 + idx * 1024), 16, 0, 0); \
      }                                                                           \
    }

  STAGE(0, 0);
  __syncthreads();
  for (int kt = 0; kt < 4; ++kt) {
    if (kt < 3) STAGE(kt + 1, (kt + 1) & 1);   // overlap with compute(kt)
    const int base = (kt & 1) << 15;
    #pragma unroll
    for (int ks = 0; ks < 2; ++ks) {
      const int kb = 64 * ks + 16 * (lane >> 4);
      f16x8 af[4];
      #pragma unroll
      for (int mi = 0; mi < 4; ++mi) {
        const int rowa = 64 * wm + 16 * mi + (lane & 15);
        af[mi] = *(const f16x8*)(sm + base + rowa * 128 + (kb ^ ((rowa & 7) << 4)));
      }
      #pragma unroll
      for (int ni = 0; ni < 4; ++ni) {
        const int rowb = 64 * wn + 16 * ni + (lane & 15);
        const f16x8 bf = *(const f16x8*)(sm + base + 16384 + rowb * 128 + (kb ^ ((rowb & 7) << 4)));
        #pragma unroll
        for (int mi = 0; mi < 4; ++mi)
          acc[mi][ni] = __builtin_amdgcn_mfma_f32_16x16x32_f16(af[mi], bf, acc[mi][ni], 0, 0, 0);
      }
    }
    __syncthreads();
  }
  #undef STAGE

  // epilogue: fused BN
  #pragma unroll
  for (int mi = 0; mi < 4; ++mi) {
    #pragma unroll
    for (int rr = 0; rr < 4; ++rr) {
      const int o = o0 + 64 * wm + 16 * mi + 4 * (lane >> 4) + rr;
      const float sc = scale[o], sh = shift[o];
      #pragma unroll
      for (int ni = 0; ni < 4; ++ni) {
        const int hw = hw0 + 64 * wn + 16 * ni + (lane & 15);
        out[(((size_t)(b * COUT + o)) << 12) + hw] = acc[mi][ni][rr] * sc + sh;
      }
    }
  }
}

extern "C" void kernel_launch(void* const* d_in, const int* in_sizes, int n_in,
                              void* d_out, int out_size, void* d_ws, size_t ws_size,
                              hipStream_t stream) {
  (void)in_sizes; (void)n_in; (void)out_size;
  const float* x      = (const float*)d_in[0];
  const float* conv_w = (const float*)d_in[1];
  // d_in[2] = conv_b: cancels in train-mode BN, unused.
  const float* gamma  = (const float*)d_in[3];
  const float* beta   = (const float*)d_in[4];
  float* out = (float*)d_out;
  char* ws = (char*)d_ws;

  // ws layout
  float* noise = (float*)(ws);                              // 4 MiB
  float* G     = (float*)(ws + (4u << 20));                 // 256 KiB
  f16*   w2    = (f16*)  (ws + (4u << 20) + (256u << 10));  // 256 KiB
  float* sums  = (float*)(ws + (4u << 20) + (512u << 10));  // 1 KiB
  float* scale = (float*)(ws + (4u << 20) + (514u << 10));  // 2 KiB
  float* shift = (float*)(ws + (4u << 20) + (517u << 10));  // 2 KiB
  f16*   x2t   = (f16*)  (ws + (5u << 20));                 // 64 MiB
  float* gpart = (float*)(ws + (69u << 20));                // up to 64 MiB

  const size_t avail = ws_size > (69ull << 20) ? ws_size - (69ull << 20) : 0;
  int npart = (int)(avail / (65536ull * sizeof(float)));
  if (npart > 256) npart = 256;
  if (npart < 1) npart = 1;               // (requires ws >= ~70 MiB)
  const int useAtomic = (npart < 256) ? 1 : 0;

  hipMemsetAsync(sums, 0, 256 * sizeof(float), stream);
  if (useAtomic)
    hipMemsetAsync(gpart, 0, (size_t)npart * 65536 * sizeof(float), stream);

  k_prep   <<<4608, 256,  0, stream>>>(conv_w, noise, w2);
  k1_gram  <<<256,  1024, 0, stream>>>(x, noise, x2t, gpart, sums, npart, useAtomic);
  k_greduce<<<256,  256,  0, stream>>>(gpart, G, npart);
  k_stats  <<<COUT, 256,  0, stream>>>(G, sums, w2, gamma, beta, scale, shift);
  k_gemm   <<<4096, 256,  0, stream>>>(w2, x2t, scale, shift, out);
}

// Round 3
// 484.027 us; speedup vs baseline: 1.1372x; 1.0161x over previous
//
#include <hip/hip_runtime.h>
#include <cstdint>

// Problem constants (fixed by setup_inputs)
#define B_    32
#define CIN   256
#define COUT  512
#define HW    4096
#define NPIX  (B_ * HW)      // 131072

typedef _Float16 f16;
typedef _Float16 f16x8 __attribute__((ext_vector_type(8)));
typedef float    f32x4 __attribute__((ext_vector_type(4)));

#define NSCALE ((float)(0.1 / 4294967295.0))

// f^n(SEED) where f(s) = 65539*s + 1 mod 2^32 (exact jump-ahead, matches the
// reference's uint32 cumprod/cumsum closed form).
__device__ __forceinline__ unsigned lcg_seed_after(unsigned n) {
  unsigned A = 1u, Bc = 0u;       // accumulated affine (A,Bc)
  unsigned mA = 65539u, mB = 1u;  // f^(2^i)
  #pragma unroll
  for (int i = 0; i < 21; ++i) {
    if (n & (1u << i)) { A = mA * A; Bc = mA * Bc + mB; }
    mB = mA * mB + mB;
    mA = mA * mA;
  }
  return A * 12345u + Bc;
}

// Compile-time affine for jump-ahead by k: s -> A_k*s + C_k (mod 2^32)
constexpr unsigned lcgA(int k) { unsigned a = 1u; for (int i = 0; i < k; ++i) a *= 65539u; return a; }
constexpr unsigned lcgC(int k) { unsigned c = 0u; for (int i = 0; i < k; ++i) c = 65539u * c + 1u; return c; }
constexpr unsigned LCG_A32 = lcgA(32);
constexpr unsigned LCG_C32 = lcgC(32);

// Tile byte address: [256 c][32 p] f16, 64 B rows, 16B-chunk XOR swizzle so
// b128 frag reads (rows varying per lane, fixed k-chunk) are conflict-free.
__device__ __forceinline__ int tadr(int c, int chunk) {
  return (c << 6) + (((chunk ^ ((c >> 1) & 3)) & 3) << 4);
}

// K1: fused  x -> x2=relu(x+noise) fp16, noise computed INLINE (sequential LCG
// + constexpr jump-ahead between steps). 16 pipelined 32-px steps:
//   per step: prefetch x(s+1) -> regs | MFMA Gram(tile[cur]) | transpose-read
//   (tile[cur]) | lcg+cvt+ds_write tile[cur^1] | barrier | x2t global store.
__global__ __launch_bounds__(1024) void k1_gram(
    const float* __restrict__ x,
    f16* __restrict__ x2t, float* __restrict__ gpart,
    float* __restrict__ sums, int npart, int useAtomic) {
  __shared__ unsigned char sm[32768];  // two 16 KiB [256][32] f16 tiles
  const int t = threadIdx.x;
  const int lane = t & 63;
  const int w = t >> 6;            // 16 waves
  const int wm = w >> 2, wn = w & 3;
  const int bid = blockIdx.x;      // 256 blocks: (b, 512-px chunk)
  const int b = bid >> 3;
  const int hw0 = (bid & 7) << 9;

  // cvt mapping: thread -> (channel cL, 8 pixels p0..p0+7)
  const int cL = t >> 2;
  const int pq = t & 3;
  const int p0 = pq << 3;
  const float* xrow = x + (((size_t)(b * CIN + cL)) << 12) + hw0 + p0;
  const int wbyte = tadr(cL, pq);  // b128 write slot (chunk == pq)

  // noise seed base for this thread's first value (index cL*HW + hw0 + p0)
  unsigned sb = lcg_seed_after((unsigned)(cL * HW + hw0 + p0) + 1u);

  // transpose mapping: thread -> (pixel tp, channels c0..c0+7)
  const int tp = t & 31;
  const int c0 = (t >> 5) << 3;

  f32x4 acc[4][4];
  #pragma unroll
  for (int i = 0; i < 4; ++i)
    #pragma unroll
    for (int j = 0; j < 4; ++j)
      acc[i][j] = (f32x4){0.f, 0.f, 0.f, 0.f};
  float csum = 0.f;

  // prologue: stage step 0
  {
    const float4 xa = *(const float4*)(xrow);
    const float4 xb = *(const float4*)(xrow + 4);
    float xr[8];
    xr[0] = xa.x; xr[1] = xa.y; xr[2] = xa.z; xr[3] = xa.w;
    xr[4] = xb.x; xr[5] = xb.y; xr[6] = xb.z; xr[7] = xb.w;
    unsigned sj = sb;
    f16x8 hv;
    #pragma unroll
    for (int j = 0; j < 8; ++j) {
      hv[j] = (f16)fmaxf(fmaf((float)sj, NSCALE, xr[j]), 0.f);
      csum += (float)hv[j];
      sj = 65539u * sj + 1u;
    }
    sb = LCG_A32 * sb + LCG_C32;   // advance to step 1's base
    *(f16x8*)(sm + wbyte) = hv;
  }
  __syncthreads();

  for (int s = 0; s < 16; ++s) {
    const int base = (s & 1) << 14;
    // ---- prefetch next x chunk (consumed in cvt below, pre-barrier) ----
    float4 xa, xb;
    if (s < 15) {
      xa = *(const float4*)(xrow + (s + 1) * 32);
      xb = *(const float4*)(xrow + (s + 1) * 32 + 4);
    }
    // ---- Gram MFMA on tile[cur] (K = 32 px) ----
    {
      const int ch = lane >> 4;
      f16x8 af[4];
      #pragma unroll
      for (int mi = 0; mi < 4; ++mi)
        af[mi] = *(const f16x8*)(sm + base + tadr(wm * 64 + mi * 16 + (lane & 15), ch));
      #pragma unroll
      for (int ni = 0; ni < 4; ++ni) {
        const f16x8 bf = *(const f16x8*)(sm + base + tadr(wn * 64 + ni * 16 + (lane & 15), ch));
        #pragma unroll
        for (int mi = 0; mi < 4; ++mi)
          acc[mi][ni] = __builtin_amdgcn_mfma_f32_16x16x32_f16(af[mi], bf, acc[mi][ni], 0, 0, 0);
      }
    }
    // ---- transpose gather: 8 channels of pixel tp (static indices) ----
    uint4 pk;
    {
      unsigned short vals[8];
      #pragma unroll
      for (int j = 0; j < 8; ++j) {
        const int row = c0 + j;
        const int addr = base + (row << 6) + ((2 * tp) & 15) +
                         ((((tp >> 3) ^ ((row >> 1) & 3)) & 3) << 4);
        vals[j] = *(const unsigned short*)(sm + addr);
      }
      pk.x = (unsigned)vals[0] | ((unsigned)vals[1] << 16);
      pk.y = (unsigned)vals[2] | ((unsigned)vals[3] << 16);
      pk.z = (unsigned)vals[4] | ((unsigned)vals[5] << 16);
      pk.w = (unsigned)vals[6] | ((unsigned)vals[7] << 16);
    }
    // ---- lcg + cvt step s+1 into the other buffer ----
    if (s < 15) {
      float xr[8];
      xr[0] = xa.x; xr[1] = xa.y; xr[2] = xa.z; xr[3] = xa.w;
      xr[4] = xb.x; xr[5] = xb.y; xr[6] = xb.z; xr[7] = xb.w;
      unsigned sj = sb;
      f16x8 hv;
      #pragma unroll
      for (int j = 0; j < 8; ++j) {
        hv[j] = (f16)fmaxf(fmaf((float)sj, NSCALE, xr[j]), 0.f);
        csum += (float)hv[j];
        sj = 65539u * sj + 1u;
      }
      sb = LCG_A32 * sb + LCG_C32;
      *(f16x8*)(sm + (base ^ 16384) + wbyte) = hv;
    }
    __syncthreads();
    // ---- x2t store for step s (fire-and-forget, drained by next barrier) ----
    *(uint4*)((char*)x2t + ((size_t)(b * HW + hw0 + s * 32 + tp)) * 512 + (c0 << 1)) = pk;
  }

  // ---- Gram partial writeback: C/D col=lane&15, row=(lane>>4)*4+reg (m91) ----
  {
    float* gp = gpart + (size_t)(bid % npart) * 65536;
    if (useAtomic) {
      #pragma unroll
      for (int mi = 0; mi < 4; ++mi)
        #pragma unroll
        for (int ni = 0; ni < 4; ++ni)
          #pragma unroll
          for (int r = 0; r < 4; ++r) {
            const int m = 64 * wm + 16 * mi + 4 * (lane >> 4) + r;
            const int n = 64 * wn + 16 * ni + (lane & 15);
            atomicAdd(&gp[m * 256 + n], acc[mi][ni][r]);
          }
    } else {
      #pragma unroll
      for (int mi = 0; mi < 4; ++mi)
        #pragma unroll
        for (int ni = 0; ni < 4; ++ni)
          #pragma unroll
          for (int r = 0; r < 4; ++r) {
            const int m = 64 * wm + 16 * mi + 4 * (lane >> 4) + r;
            const int n = 64 * wn + 16 * ni + (lane & 15);
            gp[m * 256 + n] = acc[mi][ni][r];
          }
    }
  }
  // ---- channel sums reduce (tile LDS is dead after final barrier) ----
  {
    float* sl = (float*)sm;  // [256][4]
    sl[(cL << 2) + pq] = csum;
    __syncthreads();
    if (t < 256) {
      const float* r4 = sl + (t << 2);
      atomicAdd(&sums[t], (r4[0] + r4[1]) + (r4[2] + r4[3]));
    }
  }
}

// K2a: reduce Gram partials into zero-initialized G. Grid (256, 8) for full
// occupancy (the old 1-D version was latency-bound at 4 waves/CU). blockIdx.y
// slices the partials; 8-way atomic contention per G element is negligible.
// Also folds the conv_w -> f16 conversion (runs before k_stats / k_gemm).
__global__ __launch_bounds__(256) void k_greduce(
    const float* __restrict__ gpart, float* __restrict__ G,
    const float* __restrict__ conv_w, f16* __restrict__ w2, int npart) {
  const int i = blockIdx.x * 256 + threadIdx.x;   // 0..65535
  const int nk = (npart + 7) >> 3;
  const int k0 = blockIdx.y * nk;
  int k1e = k0 + nk; if (k1e > npart) k1e = npart;
  float s0 = 0.f, s1 = 0.f, s2 = 0.f, s3 = 0.f;
  int k = k0;
  for (; k + 4 <= k1e; k += 4) {
    s0 += gpart[(size_t)(k + 0) * 65536 + i];
    s1 += gpart[(size_t)(k + 1) * 65536 + i];
    s2 += gpart[(size_t)(k + 2) * 65536 + i];
    s3 += gpart[(size_t)(k + 3) * 65536 + i];
  }
  for (; k < k1e; ++k) s0 += gpart[(size_t)k * 65536 + i];
  atomicAdd(&G[i], (s0 + s1) + (s2 + s3));
  if (blockIdx.y == 0) {
    const float2 wv = *(const float2*)(conv_w + 2 * i);
    union { f16 h[2]; unsigned u; } p;
    p.h[0] = (f16)wv.x; p.h[1] = (f16)wv.y;
    *(unsigned*)(w2 + 2 * i) = p.u;
  }
}

// K2b: per-o BN fold:  u = w.s/N, var = (w^T G w)/N - u^2,
//      scale = gamma*rsqrt(var+eps), shift = beta - u*scale  (conv_b cancels)
__global__ __launch_bounds__(256) void k_stats(
    const float* __restrict__ G, const float* __restrict__ sums,
    const f16* __restrict__ w2, const float* __restrict__ gamma,
    const float* __restrict__ beta, float* __restrict__ scale,
    float* __restrict__ shift) {
  const int o = blockIdx.x, c = threadIdx.x;
  const float wc = (float)w2[o * 256 + c];
  const float4* G4 = (const float4*)(G + (c << 8));
  const f16* wr = w2 + o * 256;
  float tc = 0.f;
  #pragma unroll 4
  for (int j8 = 0; j8 < 32; ++j8) {
    const f16x8 wv = *(const f16x8*)(wr + j8 * 8);
    const float4 ga = G4[2 * j8], gb = G4[2 * j8 + 1];
    tc += ga.x * (float)wv[0] + ga.y * (float)wv[1] + ga.z * (float)wv[2] + ga.w * (float)wv[3]
        + gb.x * (float)wv[4] + gb.y * (float)wv[5] + gb.z * (float)wv[6] + gb.w * (float)wv[7];
  }
  float q = wc * tc;
  float uv = wc * sums[c];
  #pragma unroll
  for (int off = 32; off > 0; off >>= 1) {
    q  += __shfl_down(q, off);
    uv += __shfl_down(uv, off);
  }
  __shared__ float rq[4], ru[4];
  const int lane = c & 63, w = c >> 6;
  if (lane == 0) { rq[w] = q; ru[w] = uv; }
  __syncthreads();
  if (c == 0) {
    const float Q = rq[0] + rq[1] + rq[2] + rq[3];
    const float U = ru[0] + ru[1] + ru[2] + ru[3];
    const float invN = 1.f / (float)NPIX;
    const float u = U * invN;
    const float var = Q * invN - u * u;
    const float sc = gamma[o] * rsqrtf(var + 1e-5f);
    scale[o] = sc;
    shift[o] = beta[o] - u * sc;
  }
}

// K3: out[b][o][hw] = (w2 . x2t) * scale[o] + shift[o]
// 128x128 tile, BK=64, 4 waves; double-buffered global_load_lds (T3-min):
// stage(kt+1) issued before compute(kt), one barrier per kt. XOR swizzle
// pre-applied to the GLOBAL source (LDS dest stays linear). T1 XCD swizzle.
__global__ __launch_bounds__(256) void k_gemm(
    const f16* __restrict__ w2, const f16* __restrict__ x2t,
    const float* __restrict__ scale, const float* __restrict__ shift,
    float* __restrict__ out) {
  __shared__ unsigned char sm[65536];  // buf0: A@0 B@16384; buf1: A@32768 B@49152
  const int t = threadIdx.x, lane = t & 63, w = t >> 6;
  const int wm = w >> 1, wn = w & 1;
  // T1: 4096 blocks = 8 XCDs x 512; siblings (same x2t panel) share an XCD L2.
  const int bid = (blockIdx.x & 7) * 512 + (blockIdx.x >> 3);
  const int ot = bid & 3;
  const int pt = bid >> 2;
  const int b = pt >> 5;
  const int hw0 = (pt & 31) << 7;
  const int o0 = ot << 7;
  const size_t gp0 = (size_t)b * HW + hw0;

  f32x4 acc[4][4];
  #pragma unroll
  for (int i = 0; i < 4; ++i)
    #pragma unroll
    for (int j = 0; j < 4; ++j)
      acc[i][j] = (f32x4){0.f, 0.f, 0.f, 0.f};

  const int r  = lane >> 3;          // 0..7  (row within 8-row group)
  const int cb = (lane & 7) << 4;    // 0..112 (16B column)
  const int cbs = cb ^ (r << 4);     // pre-swizzled global column

  #define STAGE(kt, buf)                                                          \
    {                                                                             \
      const int bb = (buf) << 15;                                                 \
      _Pragma("unroll")                                                           \
      for (int it = 0; it < 4; ++it) {                                            \
        const int idx = it * 4 + w;                                               \
        const int row = idx * 8 + r;                                              \
        const char* sa = (const char*)w2 + (size_t)(o0 + row) * 512 + (kt) * 128 + cbs; \
        __builtin_amdgcn_global_load_lds(                                         \
            (const __attribute__((address_space(1))) void*)sa,                    \
            (__attribute__((address_space(3))) void*)(sm + bb + idx * 1024), 16, 0, 0); \
        const char* sb = (const char*)x2t + (gp0 + row) * 512 + (kt) * 128 + cbs; \
        __builtin_amdgcn_global_load_lds(                                         \
            (const __attribute__((address_space(1))) void*)sb,                    \
            (__attribute__((address_space(3))) void*)(sm + bb + 16384 + idx * 1024), 16, 0, 0); \
      }                                                                           \
    }

  STAGE(0, 0);
  __syncthreads();
  for (int kt = 0; kt < 4; ++kt) {
    if (kt < 3) STAGE(kt + 1, (kt + 1) & 1);   // overlap with compute(kt)
    const int base = (kt & 1) << 15;
    #pragma unroll
    for (int ks = 0; ks < 2; ++ks) {
      const int kb = 64 * ks + 16 * (lane >> 4);
      f16x8 af[4];
      #pragma unroll
      for (int mi = 0; mi < 4; ++mi) {
        const int rowa = 64 * wm + 16 * mi + (lane & 15);
        af[mi] = *(const f16x8*)(sm + base + rowa * 128 + (kb ^ ((rowa & 7) << 4)));
      }
      #pragma unroll
      for (int ni = 0; ni < 4; ++ni) {
        const int rowb = 64 * wn + 16 * ni + (lane & 15);
        const f16x8 bf = *(const f16x8*)(sm + base + 16384 + rowb * 128 + (kb ^ ((rowb & 7) << 4)));
        #pragma unroll
        for (int mi = 0; mi < 4; ++mi)
          acc[mi][ni] = __builtin_amdgcn_mfma_f32_16x16x32_f16(af[mi], bf, acc[mi][ni], 0, 0, 0);
      }
    }
    __syncthreads();
  }
  #undef STAGE

  // epilogue: fused BN
  #pragma unroll
  for (int mi = 0; mi < 4; ++mi) {
    #pragma unroll
    for (int rr = 0; rr < 4; ++rr) {
      const int o = o0 + 64 * wm + 16 * mi + 4 * (lane >> 4) + rr;
      const float sc = scale[o], sh = shift[o];
      #pragma unroll
      for (int ni = 0; ni < 4; ++ni) {
        const int hw = hw0 + 64 * wn + 16 * ni + (lane & 15);
        out[(((size_t)(b * COUT + o)) << 12) + hw] = acc[mi][ni][rr] * sc + sh;
      }
    }
  }
}

extern "C" void kernel_launch(void* const* d_in, const int* in_sizes, int n_in,
                              void* d_out, int out_size, void* d_ws, size_t ws_size,
                              hipStream_t stream) {
  (void)in_sizes; (void)n_in; (void)out_size;
  const float* x      = (const float*)d_in[0];
  const float* conv_w = (const float*)d_in[1];
  // d_in[2] = conv_b: cancels in train-mode BN, unused.
  const float* gamma  = (const float*)d_in[3];
  const float* beta   = (const float*)d_in[4];
  float* out = (float*)d_out;
  char* ws = (char*)d_ws;

  // ws layout
  float* G     = (float*)(ws);                  // 256 KiB (zeroed)
  float* sums  = (float*)(ws + 262144);         // 1 KiB (zeroed)
  float* scale = (float*)(ws + 263168);         // 2 KiB
  float* shift = (float*)(ws + 265216);         // 2 KiB
  f16*   w2    = (f16*)  (ws + 267264);         // 256 KiB
  f16*   x2t   = (f16*)  (ws + (1u << 20));     // 64 MiB
  float* gpart = (float*)(ws + (65u << 20));    // up to 64 MiB

  const size_t avail = ws_size > (65ull << 20) ? ws_size - (65ull << 20) : 0;
  int npart = (int)(avail / (65536ull * sizeof(float)));
  if (npart > 256) npart = 256;
  if (npart < 1) npart = 1;               // (requires ws >= ~66 MiB)
  const int useAtomic = (npart < 256) ? 1 : 0;

  hipMemsetAsync(ws, 0, 263168, stream);  // G + sums
  if (useAtomic)
    hipMemsetAsync(gpart, 0, (size_t)npart * 65536 * sizeof(float), stream);

  k1_gram  <<<256, 1024, 0, stream>>>(x, x2t, gpart, sums, npart, useAtomic);
  k_greduce<<<dim3(256, 8), 256, 0, stream>>>(gpart, G, conv_w, w2, npart);
  k_stats  <<<COUT, 256, 0, stream>>>(G, sums, w2, gamma, beta, scale, shift);
  k_gemm   <<<4096, 256, 0, stream>>>(w2, x2t, scale, shift, out);
}

// Round 5
// 458.499 us; speedup vs baseline: 1.2005x; 1.0557x over previous
//
#include <hip/hip_runtime.h>
#include <cstdint>

// Problem constants (fixed by setup_inputs)
#define B_    32
#define CIN   256
#define COUT  512
#define HW    4096
#define NPIX  (B_ * HW)      // 131072

typedef _Float16 f16;
typedef _Float16 f16x8 __attribute__((ext_vector_type(8)));
typedef float    f32x4 __attribute__((ext_vector_type(4)));

#define NSCALE ((float)(0.1 / 4294967295.0))

// f^n(SEED) where f(s) = 65539*s + 1 mod 2^32 (exact jump-ahead, matches the
// reference's uint32 cumprod/cumsum closed form).
__device__ __forceinline__ unsigned lcg_seed_after(unsigned n) {
  unsigned A = 1u, Bc = 0u;       // accumulated affine (A,Bc)
  unsigned mA = 65539u, mB = 1u;  // f^(2^i)
  #pragma unroll
  for (int i = 0; i < 21; ++i) {
    if (n & (1u << i)) { A = mA * A; Bc = mA * Bc + mB; }
    mB = mA * mB + mB;
    mA = mA * mA;
  }
  return A * 12345u + Bc;
}

// Compile-time affine for jump-ahead by k: s -> A_k*s + C_k (mod 2^32)
constexpr unsigned lcgA(int k) { unsigned a = 1u; for (int i = 0; i < k; ++i) a *= 65539u; return a; }
constexpr unsigned lcgC(int k) { unsigned c = 0u; for (int i = 0; i < k; ++i) c = 65539u * c + 1u; return c; }
constexpr unsigned LCG_A32 = lcgA(32);
constexpr unsigned LCG_C32 = lcgC(32);

// Tile byte address: [256 c][32 p] f16, 64 B rows, 16B-chunk XOR swizzle so
// b128 frag reads (rows varying per lane, fixed k-chunk) are conflict-free.
__device__ __forceinline__ int tadr(int c, int chunk) {
  return (c << 6) + (((chunk ^ ((c >> 1) & 3)) & 3) << 4);
}

// K1: fused  x -> x2=relu(x+noise) fp16, noise computed INLINE (sequential LCG
// + constexpr jump-ahead between steps). 16 pipelined 32-px steps:
//   per step: prefetch x(s+1) -> regs | MFMA Gram(tile[cur]) | transpose-read
//   (tile[cur]) | lcg+cvt+ds_write tile[cur^1] | barrier | x2t global store.
__global__ __launch_bounds__(1024) void k1_gram(
    const float* __restrict__ x,
    f16* __restrict__ x2t, float* __restrict__ gpart,
    float* __restrict__ sums, int npart, int useAtomic) {
  __shared__ unsigned char sm[32768];  // two 16 KiB [256][32] f16 tiles
  const int t = threadIdx.x;
  const int lane = t & 63;
  const int w = t >> 6;            // 16 waves
  const int wm = w >> 2, wn = w & 3;
  const int bid = blockIdx.x;      // 256 blocks: (b, 512-px chunk)
  const int b = bid >> 3;
  const int hw0 = (bid & 7) << 9;

  // cvt mapping: thread -> (channel cL, 8 pixels p0..p0+7)
  const int cL = t >> 2;
  const int pq = t & 3;
  const int p0 = pq << 3;
  const float* xrow = x + (((size_t)(b * CIN + cL)) << 12) + hw0 + p0;
  const int wbyte = tadr(cL, pq);  // b128 write slot (chunk == pq)

  // noise seed base for this thread's first value (index cL*HW + hw0 + p0)
  unsigned sb = lcg_seed_after((unsigned)(cL * HW + hw0 + p0) + 1u);

  // transpose mapping: thread -> (pixel tp, channels c0..c0+7)
  const int tp = t & 31;
  const int c0 = (t >> 5) << 3;

  f32x4 acc[4][4];
  #pragma unroll
  for (int i = 0; i < 4; ++i)
    #pragma unroll
    for (int j = 0; j < 4; ++j)
      acc[i][j] = (f32x4){0.f, 0.f, 0.f, 0.f};
  float csum = 0.f;

  // prologue: stage step 0
  {
    const float4 xa = *(const float4*)(xrow);
    const float4 xb = *(const float4*)(xrow + 4);
    float xr[8];
    xr[0] = xa.x; xr[1] = xa.y; xr[2] = xa.z; xr[3] = xa.w;
    xr[4] = xb.x; xr[5] = xb.y; xr[6] = xb.z; xr[7] = xb.w;
    unsigned sj = sb;
    f16x8 hv;
    #pragma unroll
    for (int j = 0; j < 8; ++j) {
      hv[j] = (f16)fmaxf(fmaf((float)sj, NSCALE, xr[j]), 0.f);
      csum += (float)hv[j];
      sj = 65539u * sj + 1u;
    }
    sb = LCG_A32 * sb + LCG_C32;   // advance to step 1's base
    *(f16x8*)(sm + wbyte) = hv;
  }
  __syncthreads();

  for (int s = 0; s < 16; ++s) {
    const int base = (s & 1) << 14;
    // ---- prefetch next x chunk (consumed in cvt below, pre-barrier) ----
    float4 xa, xb;
    if (s < 15) {
      xa = *(const float4*)(xrow + (s + 1) * 32);
      xb = *(const float4*)(xrow + (s + 1) * 32 + 4);
    }
    // ---- Gram MFMA on tile[cur] (K = 32 px) ----
    {
      const int ch = lane >> 4;
      f16x8 af[4];
      #pragma unroll
      for (int mi = 0; mi < 4; ++mi)
        af[mi] = *(const f16x8*)(sm + base + tadr(wm * 64 + mi * 16 + (lane & 15), ch));
      #pragma unroll
      for (int ni = 0; ni < 4; ++ni) {
        const f16x8 bf = *(const f16x8*)(sm + base + tadr(wn * 64 + ni * 16 + (lane & 15), ch));
        #pragma unroll
        for (int mi = 0; mi < 4; ++mi)
          acc[mi][ni] = __builtin_amdgcn_mfma_f32_16x16x32_f16(af[mi], bf, acc[mi][ni], 0, 0, 0);
      }
    }
    // ---- transpose gather: 8 channels of pixel tp (static indices) ----
    uint4 pk;
    {
      unsigned short vals[8];
      #pragma unroll
      for (int j = 0; j < 8; ++j) {
        const int row = c0 + j;
        const int addr = base + (row << 6) + ((2 * tp) & 15) +
                         ((((tp >> 3) ^ ((row >> 1) & 3)) & 3) << 4);
        vals[j] = *(const unsigned short*)(sm + addr);
      }
      pk.x = (unsigned)vals[0] | ((unsigned)vals[1] << 16);
      pk.y = (unsigned)vals[2] | ((unsigned)vals[3] << 16);
      pk.z = (unsigned)vals[4] | ((unsigned)vals[5] << 16);
      pk.w = (unsigned)vals[6] | ((unsigned)vals[7] << 16);
    }
    // ---- lcg + cvt step s+1 into the other buffer ----
    if (s < 15) {
      float xr[8];
      xr[0] = xa.x; xr[1] = xa.y; xr[2] = xa.z; xr[3] = xa.w;
      xr[4] = xb.x; xr[5] = xb.y; xr[6] = xb.z; xr[7] = xb.w;
      unsigned sj = sb;
      f16x8 hv;
      #pragma unroll
      for (int j = 0; j < 8; ++j) {
        hv[j] = (f16)fmaxf(fmaf((float)sj, NSCALE, xr[j]), 0.f);
        csum += (float)hv[j];
        sj = 65539u * sj + 1u;
      }
      sb = LCG_A32 * sb + LCG_C32;
      *(f16x8*)(sm + (base ^ 16384) + wbyte) = hv;
    }
    __syncthreads();
    // ---- x2t store for step s (fire-and-forget, drained by next barrier) ----
    *(uint4*)((char*)x2t + ((size_t)(b * HW + hw0 + s * 32 + tp)) * 512 + (c0 << 1)) = pk;
  }

  // ---- Gram partial writeback: C/D col=lane&15, row=(lane>>4)*4+reg (m91) ----
  // Nontemporal: gpart is read exactly once (by k_greduce), don't pollute L2.
  {
    float* gp = gpart + (size_t)(bid % npart) * 65536;
    if (useAtomic) {
      #pragma unroll
      for (int mi = 0; mi < 4; ++mi)
        #pragma unroll
        for (int ni = 0; ni < 4; ++ni)
          #pragma unroll
          for (int r = 0; r < 4; ++r) {
            const int m = 64 * wm + 16 * mi + 4 * (lane >> 4) + r;
            const int n = 64 * wn + 16 * ni + (lane & 15);
            atomicAdd(&gp[m * 256 + n], acc[mi][ni][r]);
          }
    } else {
      #pragma unroll
      for (int mi = 0; mi < 4; ++mi)
        #pragma unroll
        for (int ni = 0; ni < 4; ++ni)
          #pragma unroll
          for (int r = 0; r < 4; ++r) {
            const int m = 64 * wm + 16 * mi + 4 * (lane >> 4) + r;
            const int n = 64 * wn + 16 * ni + (lane & 15);
            __builtin_nontemporal_store(acc[mi][ni][r], &gp[m * 256 + n]);
          }
    }
  }
  // ---- channel sums reduce (tile LDS is dead after final barrier) ----
  {
    float* sl = (float*)sm;  // [256][4]
    sl[(cL << 2) + pq] = csum;
    __syncthreads();
    if (t < 256) {
      const float* r4 = sl + (t << 2);
      atomicAdd(&sums[t], (r4[0] + r4[1]) + (r4[2] + r4[3]));
    }
  }
}

// K2a: reduce Gram partials into zero-initialized G. Grid (64, 8), f32x4
// nontemporal loads (gpart is stream-once; clang ext-vector, not HIP float4 —
// the builtin rejects HIP_vector_type). blockIdx.y slices partials; 8-way
// atomic contention per element is negligible. Folds conv_w -> f16 (8/thread).
__global__ __launch_bounds__(256) void k_greduce(
    const float* __restrict__ gpart, float* __restrict__ G,
    const float* __restrict__ conv_w, f16* __restrict__ w2, int npart) {
  const int i4 = blockIdx.x * 256 + threadIdx.x;   // 0..16383 -> floats 4*i4..+3
  const int nk = (npart + 7) >> 3;
  const int k0 = blockIdx.y * nk;
  int k1e = k0 + nk; if (k1e > npart) k1e = npart;
  f32x4 s = (f32x4){0.f, 0.f, 0.f, 0.f};
  for (int k = k0; k < k1e; ++k) {
    const f32x4 v = __builtin_nontemporal_load(
        (const f32x4*)(gpart + (size_t)k * 65536 + 4 * (size_t)i4));
    s += v;
  }
  atomicAdd(&G[4 * i4 + 0], s[0]);
  atomicAdd(&G[4 * i4 + 1], s[1]);
  atomicAdd(&G[4 * i4 + 2], s[2]);
  atomicAdd(&G[4 * i4 + 3], s[3]);
  if (blockIdx.y == 0) {
    // conv_w -> f16: 16384 threads * 8 = 131072 ✓
    const float4 wa = *(const float4*)(conv_w + 8 * i4);
    const float4 wb = *(const float4*)(conv_w + 8 * i4 + 4);
    f16x8 hv;
    hv[0] = (f16)wa.x; hv[1] = (f16)wa.y; hv[2] = (f16)wa.z; hv[3] = (f16)wa.w;
    hv[4] = (f16)wb.x; hv[5] = (f16)wb.y; hv[6] = (f16)wb.z; hv[7] = (f16)wb.w;
    *(f16x8*)(w2 + 8 * i4) = hv;
  }
}

// K2b: per-o BN fold:  u = w.s/N, var = (w^T G w)/N - u^2,
//      scale = gamma*rsqrt(var+eps), shift = beta - u*scale  (conv_b cancels)
__global__ __launch_bounds__(256) void k_stats(
    const float* __restrict__ G, const float* __restrict__ sums,
    const f16* __restrict__ w2, const float* __restrict__ gamma,
    const float* __restrict__ beta, float* __restrict__ scale,
    float* __restrict__ shift) {
  const int o = blockIdx.x, c = threadIdx.x;
  const float wc = (float)w2[o * 256 + c];
  const float4* G4 = (const float4*)(G + (c << 8));
  const f16* wr = w2 + o * 256;
  float tc = 0.f;
  #pragma unroll 4
  for (int j8 = 0; j8 < 32; ++j8) {
    const f16x8 wv = *(const f16x8*)(wr + j8 * 8);
    const float4 ga = G4[2 * j8], gb = G4[2 * j8 + 1];
    tc += ga.x * (float)wv[0] + ga.y * (float)wv[1] + ga.z * (float)wv[2] + ga.w * (float)wv[3]
        + gb.x * (float)wv[4] + gb.y * (float)wv[5] + gb.z * (float)wv[6] + gb.w * (float)wv[7];
  }
  float q = wc * tc;
  float uv = wc * sums[c];
  #pragma unroll
  for (int off = 32; off > 0; off >>= 1) {
    q  += __shfl_down(q, off);
    uv += __shfl_down(uv, off);
  }
  __shared__ float rq[4], ru[4];
  const int lane = c & 63, w = c >> 6;
  if (lane == 0) { rq[w] = q; ru[w] = uv; }
  __syncthreads();
  if (c == 0) {
    const float Q = rq[0] + rq[1] + rq[2] + rq[3];
    const float U = ru[0] + ru[1] + ru[2] + ru[3];
    const float invN = 1.f / (float)NPIX;
    const float u = U * invN;
    const float var = Q * invN - u * u;
    const float sc = gamma[o] * rsqrtf(var + 1e-5f);
    scale[o] = sc;
    shift[o] = beta[o] - u * sc;
  }
}

// K3: out[b][o][hw] = (w2 . x2t) * scale[o] + shift[o]
// 128x128 tile, BK=64, 4 waves; double-buffered global_load_lds; XOR swizzle
// pre-applied to the GLOBAL source (LDS dest stays linear). T1 XCD swizzle.
// scale/shift prefetched pre-K-loop; out via nontemporal stores (never re-read).
__global__ __launch_bounds__(256) void k_gemm(
    const f16* __restrict__ w2, const f16* __restrict__ x2t,
    const float* __restrict__ scale, const float* __restrict__ shift,
    float* __restrict__ out) {
  __shared__ unsigned char sm[65536];  // buf0: A@0 B@16384; buf1: A@32768 B@49152
  const int t = threadIdx.x, lane = t & 63, w = t >> 6;
  const int wm = w >> 1, wn = w & 1;
  // T1: 4096 blocks = 8 XCDs x 512; siblings (same x2t panel) share an XCD L2.
  const int bid = (blockIdx.x & 7) * 512 + (blockIdx.x >> 3);
  const int ot = bid & 3;
  const int pt = bid >> 2;
  const int b = pt >> 5;
  const int hw0 = (pt & 31) << 7;
  const int o0 = ot << 7;
  const size_t gp0 = (size_t)b * HW + hw0;

  f32x4 acc[4][4];
  #pragma unroll
  for (int i = 0; i < 4; ++i)
    #pragma unroll
    for (int j = 0; j < 4; ++j)
      acc[i][j] = (f32x4){0.f, 0.f, 0.f, 0.f};

  const int r  = lane >> 3;          // 0..7  (row within 8-row group)
  const int cb = (lane & 7) << 4;    // 0..112 (16B column)
  const int cbs = cb ^ (r << 4);     // pre-swizzled global column

  #define STAGE(kt, buf)                                                          \
    {                                                                             \
      const int bb = (buf) << 15;                                                 \
      _Pragma("unroll")                                                           \
      for (int it = 0; it < 4; ++it) {                                            \
        const int idx = it * 4 + w;                                               \
        const int row = idx * 8 + r;                                              \
        const char* sa = (const char*)w2 + (size_t)(o0 + row) * 512 + (kt) * 128 + cbs; \
        __builtin_amdgcn_global_load_lds(                                         \
            (const __attribute__((address_space(1))) void*)sa,                    \
            (__attribute__((address_space(3))) void*)(sm + bb + idx * 1024), 16, 0, 0); \
        const char* sb = (const char*)x2t + (gp0 + row) * 512 + (kt) * 128 + cbs; \
        __builtin_amdgcn_global_load_lds(                                         \
            (const __attribute__((address_space(1))) void*)sb,                    \
            (__attribute__((address_space(3))) void*)(sm + bb + 16384 + idx * 1024), 16, 0, 0); \
      }                                                                           \
    }

  STAGE(0, 0);

  // Prefetch BN params while staging is in flight (ready well before epilogue).
  float4 scv[4], shv[4];
  #pragma unroll
  for (int mi = 0; mi < 4; ++mi) {
    const int ob = o0 + 64 * wm + 16 * mi + 4 * (lane >> 4);
    scv[mi] = *(const float4*)(scale + ob);
    shv[mi] = *(const float4*)(shift + ob);
  }

  __syncthreads();
  for (int kt = 0; kt < 4; ++kt) {
    if (kt < 3) STAGE(kt + 1, (kt + 1) & 1);   // overlap with compute(kt)
    const int base = (kt & 1) << 15;
    #pragma unroll
    for (int ks = 0; ks < 2; ++ks) {
      const int kb = 64 * ks + 16 * (lane >> 4);
      f16x8 af[4];
      #pragma unroll
      for (int mi = 0; mi < 4; ++mi) {
        const int rowa = 64 * wm + 16 * mi + (lane & 15);
        af[mi] = *(const f16x8*)(sm + base + rowa * 128 + (kb ^ ((rowa & 7) << 4)));
      }
      #pragma unroll
      for (int ni = 0; ni < 4; ++ni) {
        const int rowb = 64 * wn + 16 * ni + (lane & 15);
        const f16x8 bf = *(const f16x8*)(sm + base + 16384 + rowb * 128 + (kb ^ ((rowb & 7) << 4)));
        #pragma unroll
        for (int mi = 0; mi < 4; ++mi)
          acc[mi][ni] = __builtin_amdgcn_mfma_f32_16x16x32_f16(af[mi], bf, acc[mi][ni], 0, 0, 0);
      }
    }
    __syncthreads();
  }
  #undef STAGE

  // epilogue: fused BN, nontemporal stores
  #pragma unroll
  for (int mi = 0; mi < 4; ++mi) {
    #pragma unroll
    for (int rr = 0; rr < 4; ++rr) {
      const int o = o0 + 64 * wm + 16 * mi + 4 * (lane >> 4) + rr;
      const float sc = ((const float*)&scv[mi])[rr];
      const float sh = ((const float*)&shv[mi])[rr];
      #pragma unroll
      for (int ni = 0; ni < 4; ++ni) {
        const int hw = hw0 + 64 * wn + 16 * ni + (lane & 15);
        __builtin_nontemporal_store(acc[mi][ni][rr] * sc + sh,
                                    &out[(((size_t)(b * COUT + o)) << 12) + hw]);
      }
    }
  }
}

extern "C" void kernel_launch(void* const* d_in, const int* in_sizes, int n_in,
                              void* d_out, int out_size, void* d_ws, size_t ws_size,
                              hipStream_t stream) {
  (void)in_sizes; (void)n_in; (void)out_size;
  const float* x      = (const float*)d_in[0];
  const float* conv_w = (const float*)d_in[1];
  // d_in[2] = conv_b: cancels in train-mode BN, unused.
  const float* gamma  = (const float*)d_in[3];
  const float* beta   = (const float*)d_in[4];
  float* out = (float*)d_out;
  char* ws = (char*)d_ws;

  // ws layout
  float* G     = (float*)(ws);                  // 256 KiB (zeroed)
  float* sums  = (float*)(ws + 262144);         // 1 KiB (zeroed)
  float* scale = (float*)(ws + 263168);         // 2 KiB
  float* shift = (float*)(ws + 265216);         // 2 KiB
  f16*   w2    = (f16*)  (ws + 267264);         // 256 KiB
  f16*   x2t   = (f16*)  (ws + (1u << 20));     // 64 MiB
  float* gpart = (float*)(ws + (65u << 20));    // up to 64 MiB

  const size_t avail = ws_size > (65ull << 20) ? ws_size - (65ull << 20) : 0;
  int npart = (int)(avail / (65536ull * sizeof(float)));
  if (npart > 256) npart = 256;
  if (npart < 1) npart = 1;               // (requires ws >= ~66 MiB)
  const int useAtomic = (npart < 256) ? 1 : 0;

  (void)hipMemsetAsync(ws, 0, 263168, stream);  // G + sums
  if (useAtomic)
    (void)hipMemsetAsync(gpart, 0, (size_t)npart * 65536 * sizeof(float), stream);

  k1_gram  <<<256, 1024, 0, stream>>>(x, x2t, gpart, sums, npart, useAtomic);
  k_greduce<<<dim3(64, 8), 256, 0, stream>>>(gpart, G, conv_w, w2, npart);
  k_stats  <<<COUT, 256, 0, stream>>>(G, sums, w2, gamma, beta, scale, shift);
  k_gemm   <<<4096, 256, 0, stream>>>(w2, x2t, scale, shift, out);
}